// Round 4
// baseline (654.239 us; speedup 1.0000x reference)
//
#include <hip/hip_runtime.h>
#include <hip/hip_bf16.h>

typedef __hip_bfloat16 bf16;
using f32x4  = __attribute__((ext_vector_type(4))) float;
using short8 = __attribute__((ext_vector_type(8))) short;

// B=8, T=12, N=325, K=8 heads, d=64, D=512, BT=96, M=31200
#define M_ROWS   31200
#define N_TOK    325
#define D_MODEL  512
#define QKV_LD   1536

// ---------------------------------------------------------------------------
// dtype detection: device inputs are either f32 or bf16. Viewing X as 16-bit
// halves: true-bf16 N(0,1) data never has bf16-exponent >= 135 (|x|>=256);
// f32 data's low-mantissa halves are ~uniform bits (p~0.47 per half).
// flag=1 -> f32 inputs, flag=0 -> bf16 inputs.
__global__ void init_flag(int* flag) { if (threadIdx.x == 0) *flag = 0; }

__global__ void detect_dtype(const unsigned short* __restrict__ x, int* flag)
{
    int i = blockIdx.x * 256 + threadIdx.x;   // 64 blocks * 256 = 16384 halves
    unsigned short h = x[i];
    int e = (h >> 7) & 0xFF;
    if (e >= 135) atomicOr(flag, 1);
}

__device__ __forceinline__ float load_in(const void* p, size_t i, bool f32)
{
    return f32 ? ((const float*)p)[i] : __bfloat162float(((const bf16*)p)[i]);
}

// ---------------------------------------------------------------------------
// transpose weight [k][n] -> [n][k] bf16 row-major
__global__ void transpose_w(const void* __restrict__ src, bf16* __restrict__ dst,
                            int krows, int ncols, const int* __restrict__ flag)
{
    const bool f32 = (*flag != 0);
    int idx = blockIdx.x * 256 + threadIdx.x;
    if (idx >= krows * ncols) return;
    int n = idx / krows, k = idx % krows;   // dst[n][k] = src[k][n]
    dst[idx] = __float2bfloat16(load_in(src, (size_t)k * ncols + n, f32));
}

__global__ void prep_bias(const void* __restrict__ bq, const void* __restrict__ bk,
                          const void* __restrict__ bv, const void* __restrict__ b1,
                          const void* __restrict__ b2,
                          float* __restrict__ biasQKV, float* __restrict__ b1f,
                          float* __restrict__ b2f, const int* __restrict__ flag)
{
    const bool f32 = (*flag != 0);
    int i = blockIdx.x * 256 + threadIdx.x;
    if (i < 512) {
        biasQKV[i]        = load_in(bq, i, f32);
        biasQKV[512 + i]  = load_in(bk, i, f32);
        biasQKV[1024 + i] = load_in(bv, i, f32);
        b1f[i] = load_in(b1, i, f32);
        b2f[i] = load_in(b2, i, f32);
    }
}

// ---------------------------------------------------------------------------
// 128x128-tile bf16-MFMA GEMM:  C = act(A @ Bt^T + bias)
//   AMODE=1: A is raw input (f32 or bf16 per flag), k-split A0/A1 (concat)
//   AMODE=0: A is bf16 intermediate (A0 only)
//   OUTF32=1: C stored as f32 (final output); else bf16
// 4 waves (2x2), each wave 64x64 via 4x4 mfma_f32_16x16x32_bf16 frags.
template<int AMODE, int OUTF32>
__global__ __launch_bounds__(256) void gemm_bt(
    const void* __restrict__ A0v, const void* __restrict__ A1v, int ksplit, int lda,
    const bf16* __restrict__ Bt, const float* __restrict__ bias,
    void* __restrict__ Cv, int M, int Kdim, int ldc, int do_relu,
    const int* __restrict__ flag)
{
    __shared__ alignas(16) bf16 As[128 * 40];   // stride 40 elems: 2-way banks (free)
    __shared__ alignas(16) bf16 Bs[128 * 40];
    const bool af32 = (AMODE == 1) && (*flag != 0);
    const int t    = threadIdx.x;
    const int m0   = blockIdx.x * 128;
    const int n0   = blockIdx.y * 128;
    const int wave = t >> 6, lane = t & 63;
    const int wm   = (wave >> 1) * 64, wn = (wave & 1) * 64;
    const int lrow = lane & 15, lk8 = (lane >> 4) * 8;
    f32x4 acc[4][4] = {};
    const int nk = Kdim >> 5;

    for (int ks = 0; ks < nk; ++ks) {
        const int kk = ks << 5;
#pragma unroll
        for (int i = 0; i < 2; ++i) {
            int idx = t + i * 256;
            int ar  = idx >> 2, ac = (idx & 3) << 3;
            int gk  = kk + ac;
            int grow = m0 + ar;
            short8 va = {0, 0, 0, 0, 0, 0, 0, 0};
            if (grow < M) {
                const bool lo = (gk < ksplit);
                const void* base = lo ? A0v : A1v;
                size_t off = (size_t)grow * lda + (lo ? gk : (gk - ksplit));
                if (af32) {
                    const float* s = (const float*)base + off;
#pragma unroll
                    for (int j = 0; j < 8; ++j)
                        ((bf16*)&va)[j] = __float2bfloat16(s[j]);
                } else {
                    va = *(const short8*)((const bf16*)base + off);
                }
            }
            *(short8*)&As[ar * 40 + ac] = va;
            *(uint4*)&Bs[ar * 40 + ac] =
                *(const uint4*)(Bt + (size_t)(n0 + ar) * Kdim + gk);
        }
        __syncthreads();
        short8 af[4], bfr[4];
#pragma unroll
        for (int i = 0; i < 4; ++i) {
            af[i]  = *(const short8*)&As[(wm + i * 16 + lrow) * 40 + lk8];
            bfr[i] = *(const short8*)&Bs[(wn + i * 16 + lrow) * 40 + lk8];
        }
#pragma unroll
        for (int i = 0; i < 4; ++i)
#pragma unroll
            for (int j = 0; j < 4; ++j)
                acc[i][j] = __builtin_amdgcn_mfma_f32_16x16x32_bf16(
                    af[i], bfr[j], acc[i][j], 0, 0, 0);
        __syncthreads();
    }

    // epilogue: D layout col = lane&15, row = (lane>>4)*4 + r
    const int r4 = (lane >> 4) * 4;
#pragma unroll
    for (int i = 0; i < 4; ++i) {
#pragma unroll
        for (int r = 0; r < 4; ++r) {
            int grow = m0 + wm + i * 16 + r4 + r;
            if (grow >= M) continue;
#pragma unroll
            for (int j = 0; j < 4; ++j) {
                int gcol = n0 + wn + j * 16 + lrow;
                float v  = acc[i][j][r] + bias[gcol];
                if (do_relu) v = fmaxf(v, 0.0f);
                if (OUTF32)
                    ((float*)Cv)[(size_t)grow * ldc + gcol] = v;
                else
                    ((bf16*)Cv)[(size_t)grow * ldc + gcol] = __float2bfloat16(v);
            }
        }
    }
}

// ---------------------------------------------------------------------------
// Attention: one block per (16-row tile, head, bt). 256 threads, 4 waves.
// ctx (bf16) is written into the q-slice of qkv (this block's own rows/cols;
// sole reader == sole writer == this block, so aliasing is safe).
// attn output written as f32 directly to d_out's attn region.
__global__ __launch_bounds__(256) void attn_kernel(
    bf16* __restrict__ qkv, float* __restrict__ attn_out)
{
    __shared__ alignas(16) bf16  qs[16 * 72];
    __shared__ alignas(16) bf16  kvs[64 * 72];
    __shared__ alignas(16) float sc[16 * 385];
    __shared__ alignas(16) bf16  pa[16 * 392];
    const int t = threadIdx.x, lane = t & 63, wave = t >> 6;
    const int rt = blockIdx.x, h = blockIdx.y, bt = blockIdx.z;
    const int r0 = rt * 16;
    const size_t rowbase = (size_t)bt * N_TOK;
    const int lrow = lane & 15, lk8 = (lane >> 4) * 8;

    // stage q tile: 16 rows x 64 elems (128 threads x 8 elems)
    if (t < 128) {
        int rr = t >> 3, e0 = (t & 7) << 3;
        int n  = r0 + rr;
        uint4 v = make_uint4(0u, 0u, 0u, 0u);
        if (n < N_TOK)
            v = *(const uint4*)(qkv + (rowbase + n) * QKV_LD + h * 64 + e0);
        *(uint4*)&qs[rr * 72 + e0] = v;
    }
    const int nmaxm   = min(r0 + 15, N_TOK - 1);
    const int nchunks = (nmaxm >> 6) + 1;

    // ---- Phase A: scores = q @ k^T
    for (int c = 0; c < nchunks; ++c) {
        const int m0 = c << 6;
        __syncthreads();
#pragma unroll
        for (int rep = 0; rep < 2; ++rep) {       // 64 rows x 64 elems
            int idx = t + rep * 256;
            int mr  = idx >> 3, e0 = (idx & 7) << 3;
            int m   = m0 + mr;
            uint4 v = make_uint4(0u, 0u, 0u, 0u);
            if (m < N_TOK)
                v = *(const uint4*)(qkv + (rowbase + m) * QKV_LD + 512 + h * 64 + e0);
            *(uint4*)&kvs[mr * 72 + e0] = v;
        }
        __syncthreads();
        f32x4 a = {0.f, 0.f, 0.f, 0.f};
#pragma unroll
        for (int kss = 0; kss < 2; ++kss) {
            short8 qa = *(const short8*)&qs[lrow * 72 + kss * 32 + lk8];
            short8 kb = *(const short8*)&kvs[(wave * 16 + lrow) * 72 + kss * 32 + lk8];
            a = __builtin_amdgcn_mfma_f32_16x16x32_bf16(qa, kb, a, 0, 0, 0);
        }
        const int r4 = (lane >> 4) * 4;
#pragma unroll
        for (int r = 0; r < 4; ++r)
            sc[(r4 + r) * 385 + m0 + wave * 16 + lrow] = a[r];
    }
    __syncthreads();

    // ---- Phase B: softmax (causal mask; scale 1/8 folded into exp)
    {
        const int row = t >> 4, sub = t & 15;
        const int n = r0 + row;
        const bool wout = (n < N_TOK);
        const int nv = wout ? n : (N_TOK - 1);
        float mx = -1e30f;
        for (int m = sub; m <= nv; m += 16)
            mx = fmaxf(mx, sc[row * 385 + m]);
#pragma unroll
        for (int o = 1; o < 16; o <<= 1) mx = fmaxf(mx, __shfl_xor(mx, o));
        float sum = 0.f;
        for (int m = sub; m <= nv; m += 16) {
            float e = __expf((sc[row * 385 + m] - mx) * 0.125f);
            sc[row * 385 + m] = e;
            sum += e;
        }
#pragma unroll
        for (int o = 1; o < 16; o <<= 1) sum += __shfl_xor(sum, o);
        float inv = 1.0f / sum;
        size_t obase = 0;
        if (wout) {
            int b = bt / 12, tt2 = bt % 12;
            obase = ((((size_t)(h * 8 + b)) * 12 + tt2) * N_TOK + n) * N_TOK;
        }
        for (int m = sub; m < 384; m += 16) {
            float v = (wout && m <= nv) ? sc[row * 385 + m] * inv : 0.f;
            pa[row * 392 + m] = __float2bfloat16(v);
            if (wout && m < N_TOK) attn_out[obase + m] = v;
        }
    }

    // ---- Phase C: ctx = attn @ v
    f32x4 acc = {0.f, 0.f, 0.f, 0.f};
    for (int c = 0; c < nchunks; ++c) {
        const int m0 = c << 6;
        __syncthreads();
#pragma unroll
        for (int rep = 0; rep < 2; ++rep) {
            int idx = t + rep * 256;
            int mr  = idx >> 3, e0 = (idx & 7) << 3;
            int m   = m0 + mr;
            uint4 v = make_uint4(0u, 0u, 0u, 0u);
            if (m < N_TOK)
                v = *(const uint4*)(qkv + (rowbase + m) * QKV_LD + 1024 + h * 64 + e0);
            *(uint4*)&kvs[mr * 72 + e0] = v;
        }
        __syncthreads();
#pragma unroll
        for (int kss = 0; kss < 2; ++kss) {
            short8 aa = *(const short8*)&pa[lrow * 392 + m0 + kss * 32 + lk8];
            short8 bb;
#pragma unroll
            for (int j = 0; j < 8; ++j)
                ((short*)&bb)[j] =
                    *(const short*)&kvs[(kss * 32 + lk8 + j) * 72 + wave * 16 + lrow];
            acc = __builtin_amdgcn_mfma_f32_16x16x32_bf16(aa, bb, acc, 0, 0, 0);
        }
    }
    __syncthreads();
    {
        const int r4 = (lane >> 4) * 4;
#pragma unroll
        for (int r = 0; r < 4; ++r) {
            int n = r0 + r4 + r;
            if (n < N_TOK) {
                int e = wave * 16 + lrow;
                qkv[(rowbase + n) * QKV_LD + h * 64 + e] = __float2bfloat16(acc[r]);
            }
        }
    }
}

// ---------------------------------------------------------------------------
extern "C" void kernel_launch(void* const* d_in, const int* in_sizes, int n_in,
                              void* d_out, int out_size, void* d_ws, size_t ws_size,
                              hipStream_t stream)
{
    const void* X   = d_in[0];
    const void* STE = d_in[1];
    const void* Wq  = d_in[2];
    const void* bq  = d_in[3];
    const void* Wk  = d_in[4];
    const void* bk  = d_in[5];
    const void* Wv  = d_in[6];
    const void* bv  = d_in[7];
    const void* W1  = d_in[8];
    const void* b1  = d_in[9];
    const void* W2  = d_in[10];
    const void* b2  = d_in[11];

    float* out0     = (float*)d_out;                              // [31200][512] f32
    float* attn_out = (float*)d_out + (size_t)M_ROWS * D_MODEL;   // [64][12][325][325] f32

    // workspace layout (bytes), total ~100.05 MB
    char* ws = (char*)d_ws;
    bf16*  qkv   = (bf16*)(ws);                      // 95,846,400
    bf16*  BtQKV = (bf16*)(ws + 95846400);           //  3,145,728
    bf16*  W1T   = (bf16*)(ws + 98992128);           //    524,288
    bf16*  W2T   = (bf16*)(ws + 99516416);           //    524,288
    float* biasQ = (float*)(ws + 100040704);         //      6,144
    float* b1f   = (float*)(ws + 100046848);         //      2,048
    float* b2f   = (float*)(ws + 100048896);         //      2,048
    int*   flag  = (int*)(ws + 100050944);           //          4
    bf16*  hbuf  = qkv + 512;                        // FFN hidden aliases k-slice (ld 1536)

    init_flag<<<1, 64, 0, stream>>>(flag);
    detect_dtype<<<64, 256, 0, stream>>>((const unsigned short*)X, flag);

    transpose_w<<<2048, 256, 0, stream>>>(Wq, BtQKV, 1024, 512, flag);
    transpose_w<<<2048, 256, 0, stream>>>(Wk, BtQKV + 512 * 1024, 1024, 512, flag);
    transpose_w<<<2048, 256, 0, stream>>>(Wv, BtQKV + 1024 * 1024, 1024, 512, flag);
    transpose_w<<<1024, 256, 0, stream>>>(W1, W1T, 512, 512, flag);
    transpose_w<<<1024, 256, 0, stream>>>(W2, W2T, 512, 512, flag);
    prep_bias<<<2, 256, 0, stream>>>(bq, bk, bv, b1, b2, biasQ, b1f, b2f, flag);

    // fused QKV projection: [31200,1024] x [1024,1536] (+bias, relu) -> bf16 ws
    gemm_bt<1, 0><<<dim3(244, 12), 256, 0, stream>>>(
        X, STE, 512, 512, BtQKV, biasQ, qkv, M_ROWS, 1024, QKV_LD, 1, flag);

    // attention (ctx -> q-slice of qkv; attn -> f32 d_out region)
    attn_kernel<<<dim3(21, 8, 96), 256, 0, stream>>>(qkv, attn_out);

    // FFN1: relu(ctx @ W1 + b1) -> hbuf (bf16, k-slice of qkv, ld 1536)
    gemm_bt<0, 0><<<dim3(244, 4), 256, 0, stream>>>(
        qkv, qkv, 512, QKV_LD, W1T, b1f, hbuf, M_ROWS, 512, QKV_LD, 1, flag);

    // FFN2: hbuf @ W2 + b2 -> out (f32)
    gemm_bt<0, 1><<<dim3(244, 4), 256, 0, stream>>>(
        hbuf, hbuf, 512, QKV_LD, W2T, b2f, out0, M_ROWS, 512, D_MODEL, 0, flag);
}